// Round 1
// baseline (258.442 us; speedup 1.0000x reference)
//
#include <hip/hip_runtime.h>
#include <stdint.h>

#define B_ 4
#define S_ 4096
#define D_ 1024
#define E_ 2048          // 2*D
#define K_ 1024
#define M_ (B_*S_)       // 16384
#define NCHAIN 32        // 128-row tiles per batch = chain length
#define SENT 0xFFFFFFFFFFFFFFFFull

typedef __bf16 bf16x8 __attribute__((ext_vector_type(8)));
typedef float  f32x4  __attribute__((ext_vector_type(4)));
typedef _Float16 f16x2 __attribute__((ext_vector_type(2)));

__device__ __forceinline__ unsigned short f2bf(float f) {
    union { float f; unsigned int u; } x; x.f = f;
    unsigned int u = x.u;
    return (unsigned short)((u + 0x7fffu + ((u >> 16) & 1u)) >> 16);
}

__device__ __forceinline__ void gload16(const void* g, void* l) {
    __builtin_amdgcn_global_load_lds(
        (const __attribute__((address_space(1))) void*)(uintptr_t)g,
        (__attribute__((address_space(3))) void*)(uintptr_t)l,
        16, 0, 0);
}

// pack (c = sigmoid(-gate), v = sigmoid(gate)*g(hidden)) as half2 in a uint
__device__ __forceinline__ unsigned int packCV(float hid, float gat) {
    float e  = __expf(gat);
    float c  = __builtin_amdgcn_rcpf(1.f + e);          // sigmoid(-gate)
    float gg = (hid >= 0.f) ? (hid + 0.5f)
                            : __builtin_amdgcn_rcpf(1.f + __expf(-hid));
    float v  = (1.f - c) * gg;                           // sigmoid(gate)*g(hidden)
    union { f16x2 h; unsigned int u; } pk;
    pk.h[0] = (_Float16)c; pk.h[1] = (_Float16)v;
    return pk.u;
}

// ---------------- merged conversion + lookback-state init kernel ----------------
// blocks [0,16384): x -> bf16 ; [16384,18432): W interleave -> bf16 ;
// [18432,18944): segAgg sentinel init (re-done every graph replay, stream-ordered
// before the fused GEMM).
__global__ void cvt_xw(const float* __restrict__ x, unsigned short* __restrict__ xb,
                       const float* __restrict__ w, unsigned short* __restrict__ wb,
                       unsigned long long* __restrict__ segAgg) {
    int b = blockIdx.x;
    if (b < 16384) {
        int i = (b * 256 + threadIdx.x) * 4;
        float4 f = *(const float4*)(x + i);
        ushort4 o;
        o.x = f2bf(f.x); o.y = f2bf(f.y); o.z = f2bf(f.z); o.w = f2bf(f.w);
        *(ushort4*)(xb + i) = o;
    } else if (b < 18432) {
        int i = ((b - 16384) * 256 + threadIdx.x) * 4;   // index into [E_, K_]
        int r = i >> 10;            // K_ = 1024
        int k = i & 1023;
        int d = r >> 1, g = r & 1;
        const float* src = w + (size_t)(g * D_ + d) * K_ + k;
        float4 f = *(const float4*)src;
        ushort4 o;
        o.x = f2bf(f.x); o.y = f2bf(f.y); o.z = f2bf(f.z); o.w = f2bf(f.w);
        *(ushort4*)(wb + i) = o;
    } else {
        int i = (b - 18432) * 256 + threadIdx.x;         // 0 .. 131071 = 2048*64
        segAgg[i] = SENT;
    }
}

// ---------------- GEMM + activation + in-block scan/apply (decoupled lookback) --
#define BM 128
#define BN 128
#define BK 32

__global__ __launch_bounds__(256, 2)
void gemm_fused(const unsigned short* __restrict__ xb,
                const unsigned short* __restrict__ wb,
                unsigned long long* __restrict__ segAgg,
                float* __restrict__ out) {
    __shared__ unsigned short As[BM * BK];                 // 8 KB
    __shared__ unsigned short Bs[BN * BK];                 // 8 KB
    __shared__ __align__(16) unsigned int Ep[4][64][36];   // 36 KB (pad 32->36)

    // ord = s*64 + batch*16 + eB: chain position s is SLOWEST so every
    // predecessor (same batch,eB, smaller s) has a strictly smaller blockIdx
    // (in-order dispatch => lookback-safe) and sits in an earlier scheduling
    // round (=> near-zero spin). Per-XCD (ord&7) gets 2 fixed eB wb-panels
    // (512 KB, L2-hot) while xb slices stream via LLC.
    const int ord  = blockIdx.x;        // 0..2047
    const int eB   = ord & 15;          // 0..15
    const int bat  = (ord >> 4) & 3;    // 0..3
    const int sIx  = ord >> 6;          // 0..31 chain position within batch
    const int mB   = bat * NCHAIN + sIx;
    const int mBase = mB * BM;
    const int eBase = eB * BN;

    const int tid  = threadIdx.x;
    const int lane = tid & 63;
    const int w    = tid >> 6;
    const int waveM = (w >> 1) * 64;
    const int waveN = (w & 1) * 64;

    f32x4 acc[4][4] = {};

    // staging: lane tid covers (row = tid>>2, 16B chunk = tid&3)
    const int row0 = tid >> 2, cu = tid & 3;
    const unsigned short* aG0 = xb + (size_t)(mBase + row0) * K_ + cu * 8;
    const unsigned short* aG1 = aG0 + (size_t)64 * K_;
    const unsigned short* bG0 = wb + (size_t)(eBase + row0) * K_ + cu * 8;
    const unsigned short* bG1 = bG0 + (size_t)64 * K_;
    // wave-uniform LDS bases (HW adds lane*16B)
    unsigned short* aL0 = As + (size_t)(w * 64) * 8;
    unsigned short* aL1 = As + (size_t)(256 + w * 64) * 8;
    unsigned short* bL0 = Bs + (size_t)(w * 64) * 8;
    unsigned short* bL1 = Bs + (size_t)(256 + w * 64) * 8;

    const int mrow = lane & 15;
    const int kg   = (lane >> 4) * 8;

    for (int k0 = 0; k0 < K_; k0 += BK) {
        __syncthreads();
        gload16(aG0 + k0, aL0);
        gload16(aG1 + k0, aL1);
        gload16(bG0 + k0, bL0);
        gload16(bG1 + k0, bL1);
        __syncthreads();

        bf16x8 af[4], bfr[4];
#pragma unroll
        for (int i = 0; i < 4; i++)
            af[i] = *(const bf16x8*)(As + (size_t)(waveM + i * 16 + mrow) * BK + kg);
#pragma unroll
        for (int j = 0; j < 4; j++)
            bfr[j] = *(const bf16x8*)(Bs + (size_t)(waveN + j * 16 + mrow) * BK + kg);
#pragma unroll
        for (int i = 0; i < 4; i++)
#pragma unroll
            for (int j = 0; j < 4; j++)
                acc[i][j] = __builtin_amdgcn_mfma_f32_16x16x32_bf16(af[i], bfr[j], acc[i][j], 0, 0, 0);
    }

    // ---- epilogue 1: activation + pack + LDS transpose ----
    const int q    = lane >> 4;
    const int odd  = lane & 1;
    const int colL = (lane & 15) >> 1;            // 0..7
    unsigned int* EpW = &Ep[w][0][0];

#pragma unroll
    for (int i = 0; i < 4; i++) {
#pragma unroll
        for (int j = 0; j < 4; j++) {
            float o0 = __shfl_xor(acc[i][j][0], 1, 64);
            float o1 = __shfl_xor(acc[i][j][1], 1, 64);
            float o2 = __shfl_xor(acc[i][j][2], 1, 64);
            float o3 = __shfl_xor(acc[i][j][3], 1, 64);
            float m0 = odd ? acc[i][j][2] : acc[i][j][0];
            float m1 = odd ? acc[i][j][3] : acc[i][j][1];
            float p0 = odd ? o2 : o0;
            float p1 = odd ? o3 : o1;
            float h0 = odd ? p0 : m0, g0 = odd ? m0 : p0;
            float h1 = odd ? p1 : m1, g1 = odd ? m1 : p1;
            int row = i * 16 + q * 4 + odd * 2;
            int col = j * 8 + colL;
            EpW[(row    ) * 36 + col] = packCV(h0, g0);
            EpW[(row + 1) * 36 + col] = packCV(h1, g1);
        }
    }

    // ---- epilogue 2: quarter reduce (32 rows x 64 ch per thread-group) ----
    __syncthreads();                      // Ep fully written; As/Bs dead -> reuse
    float* scratch = (float*)As;          // [4][64][2] floats = 2 KB
    float* hpre    = scratch + 512;       // 64 floats

    const int dl = tid & 63;              // channel 0..63 within block
    const int qt = tid >> 6;              // quarter 0..3 (rows qt*32 .. +31)
    const int wq = (qt >> 1) * 2 + (dl >> 5);
    const int rB = (qt & 1) * 32;
    const int cc_ = dl & 31;
    const unsigned int* src = &Ep[wq][rB][cc_];
    {
        float C = 1.f, V = 0.f;
#pragma unroll 8
        for (int rr = 0; rr < 32; rr++) {
            union { unsigned int u; f16x2 h; } uu;
            uu.u = src[rr * 36];
            float cv_c = (float)uu.h[0], cv_v = (float)uu.h[1];
            V = fmaf(cv_c, V, cv_v);
            C *= cv_c;
        }
        scratch[(qt * 64 + dl) * 2 + 0] = C;
        scratch[(qt * 64 + dl) * 2 + 1] = V;
    }
    __syncthreads();

    // ---- epilogue 3 (wave 0 only): publish aggregate, then lookback ----
    if (tid < 64) {
        float C0 = scratch[(0 * 64 + tid) * 2], V0 = scratch[(0 * 64 + tid) * 2 + 1];
        float C1 = scratch[(1 * 64 + tid) * 2], V1 = scratch[(1 * 64 + tid) * 2 + 1];
        float C2 = scratch[(2 * 64 + tid) * 2], V2 = scratch[(2 * 64 + tid) * 2 + 1];
        float C3 = scratch[(3 * 64 + tid) * 2], V3 = scratch[(3 * 64 + tid) * 2 + 1];
        float Cb = (C0 * C1) * (C2 * C3);
        float Vb = fmaf(C3, fmaf(C2, fmaf(C1, V0, V1), V2), V3);
        union { unsigned long long u; float f[2]; } pk;
        pk.f[0] = Cb; pk.f[1] = Vb;
        // UNCONDITIONAL publish before any wait -> no deadlock possible.
        __hip_atomic_store(&segAgg[(size_t)ord * 64 + tid], pk.u,
                           __ATOMIC_RELEASE, __HIP_MEMORY_SCOPE_AGENT);
        __threadfence();

        // aggregate-only lookback: fold predecessors t = 0..sIx-1 in order.
        float h = 0.f;
        const size_t chanB = (size_t)(ord & 63) * 64 + tid;  // (bat*16+eB)*64+ch
#pragma unroll 1
        for (int t0 = 0; t0 < NCHAIN; t0 += 8) {
            if (t0 >= sIx) break;
            unsigned long long vb[8];
#pragma unroll
            for (int k = 0; k < 8; k++)
                vb[k] = (t0 + k < sIx)
                    ? __hip_atomic_load(&segAgg[(size_t)(t0 + k) * 4096 + chanB],
                                        __ATOMIC_RELAXED, __HIP_MEMORY_SCOPE_AGENT)
                    : 0x3f800000ull;    // identity (C=1, V=0)
#pragma unroll
            for (int k = 0; k < 8; k++) {
                if (t0 + k < sIx) {
                    while (vb[k] == SENT)
                        vb[k] = __hip_atomic_load(&segAgg[(size_t)(t0 + k) * 4096 + chanB],
                                                  __ATOMIC_RELAXED, __HIP_MEMORY_SCOPE_AGENT);
                }
            }
#pragma unroll
            for (int k = 0; k < 8; k++) {
                union { unsigned long long u; float f[2]; } qd; qd.u = vb[k];
                h = fmaf(qd.f[0], h, qd.f[1]);
            }
        }
        hpre[tid] = h;
    }
    __syncthreads();

    // ---- epilogue 4: apply h_t = c_t*h_{t-1} + v_t, write out (fp32) ----
    {
        float h = hpre[dl];
        if (qt > 0) h = fmaf(scratch[(0 * 64 + dl) * 2], h, scratch[(0 * 64 + dl) * 2 + 1]);
        if (qt > 1) h = fmaf(scratch[(1 * 64 + dl) * 2], h, scratch[(1 * 64 + dl) * 2 + 1]);
        if (qt > 2) h = fmaf(scratch[(2 * 64 + dl) * 2], h, scratch[(2 * 64 + dl) * 2 + 1]);
        float* outp = out + (size_t)(mBase + qt * 32) * D_ + (eB * 64 + dl);
#pragma unroll 8
        for (int rr = 0; rr < 32; rr++) {
            union { unsigned int u; f16x2 hh; } uu;
            uu.u = src[rr * 36];
            h = fmaf((float)uu.hh[0], h, (float)uu.hh[1]);
            outp[(size_t)rr * D_] = h;
        }
    }
}

// ---------------- launch ----------------
extern "C" void kernel_launch(void* const* d_in, const int* in_sizes, int n_in,
                              void* d_out, int out_size, void* d_ws, size_t ws_size,
                              hipStream_t stream) {
    const float* x = (const float*)d_in[0];
    const float* wmat = (const float*)d_in[1];
    float* out = (float*)d_out;
    char* ws = (char*)d_ws;

    unsigned short* xb = (unsigned short*)(ws);                       // 32 MB @ 0
    unsigned short* wb = (unsigned short*)(ws + (32u << 20));         //  4 MB @ 32M
    unsigned long long* segAgg = (unsigned long long*)(ws + (36u << 20)); // 1 MB @ 36M

    cvt_xw<<<18944, 256, 0, stream>>>(x, xb, wmat, wb, segAgg);
    gemm_fused<<<2048, 256, 0, stream>>>(xb, wb, segAgg, out);
}

// Round 2
// 250.942 us; speedup vs baseline: 1.0299x; 1.0299x over previous
//
#include <hip/hip_runtime.h>
#include <stdint.h>

#define B_ 4
#define S_ 4096
#define D_ 1024
#define E_ 2048          // 2*D
#define K_ 1024
#define M_ (B_*S_)       // 16384
#define NCHAIN 32        // 128-row tiles per batch = chain length
#define SENT 0xFFFFFFFFFFFFFFFFull

typedef __bf16 bf16x8 __attribute__((ext_vector_type(8)));
typedef float  f32x4  __attribute__((ext_vector_type(4)));
typedef _Float16 f16x2 __attribute__((ext_vector_type(2)));

__device__ __forceinline__ unsigned short f2bf(float f) {
    union { float f; unsigned int u; } x; x.f = f;
    unsigned int u = x.u;
    return (unsigned short)((u + 0x7fffu + ((u >> 16) & 1u)) >> 16);
}

__device__ __forceinline__ void gload16(const void* g, void* l) {
    __builtin_amdgcn_global_load_lds(
        (const __attribute__((address_space(1))) void*)(uintptr_t)g,
        (__attribute__((address_space(3))) void*)(uintptr_t)l,
        16, 0, 0);
}

// pack (c = sigmoid(-gate), v = sigmoid(gate)*g(hidden)) as half2 in a uint
__device__ __forceinline__ unsigned int packCV(float hid, float gat) {
    float e  = __expf(gat);
    float c  = __builtin_amdgcn_rcpf(1.f + e);          // sigmoid(-gate)
    float gg = (hid >= 0.f) ? (hid + 0.5f)
                            : __builtin_amdgcn_rcpf(1.f + __expf(-hid));
    float v  = (1.f - c) * gg;                           // sigmoid(gate)*g(hidden)
    union { f16x2 h; unsigned int u; } pk;
    pk.h[0] = (_Float16)c; pk.h[1] = (_Float16)v;
    return pk.u;
}

// ---------------- conversion + lookback-state init (grid-strided, 8x ILP) -----
// blocks [0,2048): x -> bf16 (8 float4/thread)
// blocks [2048,2304): W interleave -> bf16 (8 float4/thread)
// blocks [2304,2368): segAgg sentinel init (8 u64/thread)
__global__ __launch_bounds__(256)
void cvt_xw(const float* __restrict__ x, unsigned short* __restrict__ xb,
            const float* __restrict__ w, unsigned short* __restrict__ wb,
            unsigned long long* __restrict__ segAgg) {
    const int b = blockIdx.x;
    const int t = threadIdx.x;
    if (b < 2048) {
        // x: 4,194,304 float4 total; 2048 per block; 8 per thread (indep chains)
        const float4* xp = (const float4*)x + (size_t)b * 2048 + t;
        ushort4*      op = (ushort4*)xb + (size_t)b * 2048 + t;
        float4 f[8];
#pragma unroll
        for (int k = 0; k < 8; k++) f[k] = xp[(size_t)k * 256];
#pragma unroll
        for (int k = 0; k < 8; k++) {
            ushort4 o;
            o.x = f2bf(f[k].x); o.y = f2bf(f[k].y);
            o.z = f2bf(f[k].z); o.w = f2bf(f[k].w);
            op[(size_t)k * 256] = o;
        }
    } else if (b < 2304) {
        // W: 524,288 float4 total; 2048 per block; 8 per thread
        const int base4 = (b - 2048) * 2048 + t;    // float4 index into [E_,K_]
        float4 f[8];
        const float* srcs[8];
#pragma unroll
        for (int k = 0; k < 8; k++) {
            int i = (base4 + k * 256) * 4;
            int r = i >> 10;            // row in interleaved [E_, K_]
            int kk = i & 1023;
            int d = r >> 1, g = r & 1;
            srcs[k] = w + (size_t)(g * D_ + d) * K_ + kk;
        }
#pragma unroll
        for (int k = 0; k < 8; k++) f[k] = *(const float4*)srcs[k];
#pragma unroll
        for (int k = 0; k < 8; k++) {
            int i = (base4 + k * 256) * 4;
            ushort4 o;
            o.x = f2bf(f[k].x); o.y = f2bf(f[k].y);
            o.z = f2bf(f[k].z); o.w = f2bf(f[k].w);
            *(ushort4*)(wb + i) = o;
        }
    } else {
        // sentinel: 131072 u64 = 64 blocks * 256 threads * 8
        const size_t base = (size_t)(b - 2304) * 2048 + t;
#pragma unroll
        for (int k = 0; k < 8; k++) segAgg[base + (size_t)k * 256] = SENT;
    }
}

// ---------------- GEMM + activation + in-block scan/apply (decoupled lookback) --
#define BM 128
#define BN 128
#define BK 32

__global__ __launch_bounds__(256, 2)
void gemm_fused(const unsigned short* __restrict__ xb,
                const unsigned short* __restrict__ wb,
                unsigned long long* __restrict__ segAgg,
                float* __restrict__ out) {
    __shared__ unsigned short As[BM * BK];                 // 8 KB
    __shared__ unsigned short Bs[BN * BK];                 // 8 KB
    __shared__ __align__(16) unsigned int Ep[4][64][36];   // 36 KB (pad 32->36)

    // ord = s*64 + (eB*4 + bat): chain position s is SLOWEST so every
    // predecessor (same bat,eB, smaller s) has a strictly smaller blockIdx
    // (in-order dispatch => lookback-safe, near-zero spin).
    // XCD j (= ord%8 = inner%8) gets bat = j&3 and the 8 eB panels of parity
    // j>>2: per-XCD L2 set = 2MB wb (SAME panels every round -> resident)
    // + 256KB xb slice/round shared with exactly one other XCD.
    const int ord   = blockIdx.x;       // 0..2047
    const int inner = ord & 63;
    const int eB    = inner >> 2;       // 0..15
    const int bat   = inner & 3;        // 0..3
    const int sIx   = ord >> 6;         // 0..31 chain position within batch
    const int mB    = bat * NCHAIN + sIx;
    const int mBase = mB * BM;
    const int eBase = eB * BN;

    const int tid  = threadIdx.x;
    const int lane = tid & 63;
    const int w    = tid >> 6;
    const int waveM = (w >> 1) * 64;
    const int waveN = (w & 1) * 64;

    f32x4 acc[4][4] = {};

    // staging: lane tid covers (row = tid>>2, 16B chunk = tid&3)
    const int row0 = tid >> 2, cu = tid & 3;
    const unsigned short* aG0 = xb + (size_t)(mBase + row0) * K_ + cu * 8;
    const unsigned short* aG1 = aG0 + (size_t)64 * K_;
    const unsigned short* bG0 = wb + (size_t)(eBase + row0) * K_ + cu * 8;
    const unsigned short* bG1 = bG0 + (size_t)64 * K_;
    // wave-uniform LDS bases (HW adds lane*16B)
    unsigned short* aL0 = As + (size_t)(w * 64) * 8;
    unsigned short* aL1 = As + (size_t)(256 + w * 64) * 8;
    unsigned short* bL0 = Bs + (size_t)(w * 64) * 8;
    unsigned short* bL1 = Bs + (size_t)(256 + w * 64) * 8;

    const int mrow = lane & 15;
    const int kg   = (lane >> 4) * 8;

    for (int k0 = 0; k0 < K_; k0 += BK) {
        __syncthreads();
        gload16(aG0 + k0, aL0);
        gload16(aG1 + k0, aL1);
        gload16(bG0 + k0, bL0);
        gload16(bG1 + k0, bL1);
        __syncthreads();

        bf16x8 af[4], bfr[4];
#pragma unroll
        for (int i = 0; i < 4; i++)
            af[i] = *(const bf16x8*)(As + (size_t)(waveM + i * 16 + mrow) * BK + kg);
#pragma unroll
        for (int j = 0; j < 4; j++)
            bfr[j] = *(const bf16x8*)(Bs + (size_t)(waveN + j * 16 + mrow) * BK + kg);
#pragma unroll
        for (int i = 0; i < 4; i++)
#pragma unroll
            for (int j = 0; j < 4; j++)
                acc[i][j] = __builtin_amdgcn_mfma_f32_16x16x32_bf16(af[i], bfr[j], acc[i][j], 0, 0, 0);
    }

    // ---- epilogue 1: activation + pack + LDS transpose ----
    const int q    = lane >> 4;
    const int odd  = lane & 1;
    const int colL = (lane & 15) >> 1;            // 0..7
    unsigned int* EpW = &Ep[w][0][0];

#pragma unroll
    for (int i = 0; i < 4; i++) {
#pragma unroll
        for (int j = 0; j < 4; j++) {
            float o0 = __shfl_xor(acc[i][j][0], 1, 64);
            float o1 = __shfl_xor(acc[i][j][1], 1, 64);
            float o2 = __shfl_xor(acc[i][j][2], 1, 64);
            float o3 = __shfl_xor(acc[i][j][3], 1, 64);
            float m0 = odd ? acc[i][j][2] : acc[i][j][0];
            float m1 = odd ? acc[i][j][3] : acc[i][j][1];
            float p0 = odd ? o2 : o0;
            float p1 = odd ? o3 : o1;
            float h0 = odd ? p0 : m0, g0 = odd ? m0 : p0;
            float h1 = odd ? p1 : m1, g1 = odd ? m1 : p1;
            int row = i * 16 + q * 4 + odd * 2;
            int col = j * 8 + colL;
            EpW[(row    ) * 36 + col] = packCV(h0, g0);
            EpW[(row + 1) * 36 + col] = packCV(h1, g1);
        }
    }

    // ---- epilogue 2: quarter reduce (32 rows x 64 ch per thread-group) ----
    __syncthreads();                      // Ep fully written; As/Bs dead -> reuse
    float* scratch = (float*)As;          // [4][64][2] floats = 2 KB
    float* hpre    = scratch + 512;       // 64 floats

    const int dl = tid & 63;              // channel 0..63 within block
    const int qt = tid >> 6;              // quarter 0..3 (rows qt*32 .. +31)
    const int wq = (qt >> 1) * 2 + (dl >> 5);
    const int rB = (qt & 1) * 32;
    const int cc_ = dl & 31;
    const unsigned int* src = &Ep[wq][rB][cc_];
    {
        float C = 1.f, V = 0.f;
#pragma unroll 8
        for (int rr = 0; rr < 32; rr++) {
            union { unsigned int u; f16x2 h; } uu;
            uu.u = src[rr * 36];
            float cv_c = (float)uu.h[0], cv_v = (float)uu.h[1];
            V = fmaf(cv_c, V, cv_v);
            C *= cv_c;
        }
        scratch[(qt * 64 + dl) * 2 + 0] = C;
        scratch[(qt * 64 + dl) * 2 + 1] = V;
    }
    __syncthreads();

    // ---- epilogue 3 (wave 0 only): publish aggregate, then lookback ----
    if (tid < 64) {
        float C0 = scratch[(0 * 64 + tid) * 2], V0 = scratch[(0 * 64 + tid) * 2 + 1];
        float C1 = scratch[(1 * 64 + tid) * 2], V1 = scratch[(1 * 64 + tid) * 2 + 1];
        float C2 = scratch[(2 * 64 + tid) * 2], V2 = scratch[(2 * 64 + tid) * 2 + 1];
        float C3 = scratch[(3 * 64 + tid) * 2], V3 = scratch[(3 * 64 + tid) * 2 + 1];
        float Cb = (C0 * C1) * (C2 * C3);
        float Vb = fmaf(C3, fmaf(C2, fmaf(C1, V0, V1), V2), V3);
        union { unsigned long long u; float f[2]; } pk;
        pk.f[0] = Cb; pk.f[1] = Vb;
        // UNCONDITIONAL publish before any wait -> no deadlock possible.
        __hip_atomic_store(&segAgg[(size_t)ord * 64 + tid], pk.u,
                           __ATOMIC_RELEASE, __HIP_MEMORY_SCOPE_AGENT);
        __threadfence();

        // aggregate-only lookback: fold predecessors t = 0..sIx-1 in order.
        float h = 0.f;
        const size_t chanB = (size_t)inner * 64 + tid;  // (eB*4+bat)*64+ch
#pragma unroll 1
        for (int t0 = 0; t0 < NCHAIN; t0 += 8) {
            if (t0 >= sIx) break;
            unsigned long long vb[8];
#pragma unroll
            for (int k = 0; k < 8; k++)
                vb[k] = (t0 + k < sIx)
                    ? __hip_atomic_load(&segAgg[(size_t)(t0 + k) * 4096 + chanB],
                                        __ATOMIC_RELAXED, __HIP_MEMORY_SCOPE_AGENT)
                    : 0x3f800000ull;    // identity (C=1, V=0)
#pragma unroll
            for (int k = 0; k < 8; k++) {
                if (t0 + k < sIx) {
                    while (vb[k] == SENT)
                        vb[k] = __hip_atomic_load(&segAgg[(size_t)(t0 + k) * 4096 + chanB],
                                                  __ATOMIC_RELAXED, __HIP_MEMORY_SCOPE_AGENT);
                }
            }
#pragma unroll
            for (int k = 0; k < 8; k++) {
                union { unsigned long long u; float f[2]; } qd; qd.u = vb[k];
                h = fmaf(qd.f[0], h, qd.f[1]);
            }
        }
        hpre[tid] = h;
    }
    __syncthreads();

    // ---- epilogue 4: apply h_t = c_t*h_{t-1} + v_t, write out (fp32) ----
    {
        float h = hpre[dl];
        if (qt > 0) h = fmaf(scratch[(0 * 64 + dl) * 2], h, scratch[(0 * 64 + dl) * 2 + 1]);
        if (qt > 1) h = fmaf(scratch[(1 * 64 + dl) * 2], h, scratch[(1 * 64 + dl) * 2 + 1]);
        if (qt > 2) h = fmaf(scratch[(2 * 64 + dl) * 2], h, scratch[(2 * 64 + dl) * 2 + 1]);
        float* outp = out + (size_t)(mBase + qt * 32) * D_ + (eB * 64 + dl);
#pragma unroll 8
        for (int rr = 0; rr < 32; rr++) {
            union { unsigned int u; f16x2 hh; } uu;
            uu.u = src[rr * 36];
            h = fmaf((float)uu.hh[0], h, (float)uu.hh[1]);
            outp[(size_t)rr * D_] = h;
        }
    }
}

// ---------------- launch ----------------
extern "C" void kernel_launch(void* const* d_in, const int* in_sizes, int n_in,
                              void* d_out, int out_size, void* d_ws, size_t ws_size,
                              hipStream_t stream) {
    const float* x = (const float*)d_in[0];
    const float* wmat = (const float*)d_in[1];
    float* out = (float*)d_out;
    char* ws = (char*)d_ws;

    unsigned short* xb = (unsigned short*)(ws);                       // 32 MB @ 0
    unsigned short* wb = (unsigned short*)(ws + (32u << 20));         //  4 MB @ 32M
    unsigned long long* segAgg = (unsigned long long*)(ws + (36u << 20)); // 1 MB @ 36M

    cvt_xw<<<2368, 256, 0, stream>>>(x, xb, wmat, wb, segAgg);
    gemm_fused<<<2048, 256, 0, stream>>>(xb, wb, segAgg, out);
}

// Round 3
// 201.261 us; speedup vs baseline: 1.2841x; 1.2468x over previous
//
#include <hip/hip_runtime.h>
#include <stdint.h>

#define B_ 4
#define S_ 4096
#define D_ 1024
#define E_ 2048          // 2*D
#define K_ 1024
#define M_ (B_*S_)       // 16384
#define NCHAIN 32        // 128-row tiles per batch = chain length
#define SENT 0xFFFFFFFFFFFFFFFFull

typedef __bf16 bf16x8 __attribute__((ext_vector_type(8)));
typedef float  f32x4  __attribute__((ext_vector_type(4)));
typedef _Float16 f16x2 __attribute__((ext_vector_type(2)));

__device__ __forceinline__ unsigned short f2bf(float f) {
    union { float f; unsigned int u; } x; x.f = f;
    unsigned int u = x.u;
    return (unsigned short)((u + 0x7fffu + ((u >> 16) & 1u)) >> 16);
}

__device__ __forceinline__ void gload16(const void* g, void* l) {
    __builtin_amdgcn_global_load_lds(
        (const __attribute__((address_space(1))) void*)(uintptr_t)g,
        (__attribute__((address_space(3))) void*)(uintptr_t)l,
        16, 0, 0);
}

// pack (c = sigmoid(-gate), v = sigmoid(gate)*g(hidden)) as half2 in a uint
__device__ __forceinline__ unsigned int packCV(float hid, float gat) {
    float e  = __expf(gat);
    float c  = __builtin_amdgcn_rcpf(1.f + e);          // sigmoid(-gate)
    float gg = (hid >= 0.f) ? (hid + 0.5f)
                            : __builtin_amdgcn_rcpf(1.f + __expf(-hid));
    float v  = (1.f - c) * gg;                           // sigmoid(gate)*g(hidden)
    union { f16x2 h; unsigned int u; } pk;
    pk.h[0] = (_Float16)c; pk.h[1] = (_Float16)v;
    return pk.u;
}

// ---------------- conversion + lookback-state init (grid-strided, 8x ILP) -----
// blocks [0,2048): x -> bf16 (8 float4/thread)
// blocks [2048,2304): W interleave -> bf16 (8 float4/thread)
// blocks [2304,2368): segAgg sentinel init (8 u64/thread)
__global__ __launch_bounds__(256)
void cvt_xw(const float* __restrict__ x, unsigned short* __restrict__ xb,
            const float* __restrict__ w, unsigned short* __restrict__ wb,
            unsigned long long* __restrict__ segAgg) {
    const int b = blockIdx.x;
    const int t = threadIdx.x;
    if (b < 2048) {
        // x: 4,194,304 float4 total; 2048 per block; 8 per thread (indep chains)
        const float4* xp = (const float4*)x + (size_t)b * 2048 + t;
        ushort4*      op = (ushort4*)xb + (size_t)b * 2048 + t;
        float4 f[8];
#pragma unroll
        for (int k = 0; k < 8; k++) f[k] = xp[(size_t)k * 256];
#pragma unroll
        for (int k = 0; k < 8; k++) {
            ushort4 o;
            o.x = f2bf(f[k].x); o.y = f2bf(f[k].y);
            o.z = f2bf(f[k].z); o.w = f2bf(f[k].w);
            op[(size_t)k * 256] = o;
        }
    } else if (b < 2304) {
        // W: 524,288 float4 total; 2048 per block; 8 per thread
        const int base4 = (b - 2048) * 2048 + t;    // float4 index into [E_,K_]
        float4 f[8];
        const float* srcs[8];
#pragma unroll
        for (int k = 0; k < 8; k++) {
            int i = (base4 + k * 256) * 4;
            int r = i >> 10;            // row in interleaved [E_, K_]
            int kk = i & 1023;
            int d = r >> 1, g = r & 1;
            srcs[k] = w + (size_t)(g * D_ + d) * K_ + kk;
        }
#pragma unroll
        for (int k = 0; k < 8; k++) f[k] = *(const float4*)srcs[k];
#pragma unroll
        for (int k = 0; k < 8; k++) {
            int i = (base4 + k * 256) * 4;
            ushort4 o;
            o.x = f2bf(f[k].x); o.y = f2bf(f[k].y);
            o.z = f2bf(f[k].z); o.w = f2bf(f[k].w);
            *(ushort4*)(wb + i) = o;
        }
    } else {
        // sentinel: 131072 u64 = 64 blocks * 256 threads * 8
        const size_t base = (size_t)(b - 2304) * 2048 + t;
#pragma unroll
        for (int k = 0; k < 8; k++) segAgg[base + (size_t)k * 256] = SENT;
    }
}

// ---------------- GEMM + activation + in-block scan/apply (decoupled lookback) --
#define BM 128
#define BN 128
#define BK 32

// 3 blocks/CU: regs 68+64acc=132 (3x132=396<=512/SIMD), LDS 3x52KB=156<=160KB.
__global__ __launch_bounds__(256, 3)
void gemm_fused(const unsigned short* __restrict__ xb,
                const unsigned short* __restrict__ wb,
                unsigned long long* __restrict__ segAgg,
                float* __restrict__ out) {
    __shared__ unsigned short As[BM * BK];                 // 8 KB
    __shared__ unsigned short Bs[BN * BK];                 // 8 KB
    __shared__ __align__(16) unsigned int Ep[4][64][36];   // 36 KB (pad 32->36)

    // ord = s*64 + (eB*4 + bat): chain position s is SLOWEST so every
    // predecessor (same bat,eB, smaller s) has a strictly smaller blockIdx
    // (in-order dispatch => lookback-safe, near-zero spin).
    // XCD j (= ord%8 = inner%8) gets bat = j&3 and the 8 eB panels of parity
    // j>>2: per-XCD L2 set = 2MB wb (SAME panels every round -> resident)
    // + 256KB xb slice/round shared with exactly one other XCD.
    const int ord   = blockIdx.x;       // 0..2047
    const int inner = ord & 63;
    const int eB    = inner >> 2;       // 0..15
    const int bat   = inner & 3;        // 0..3
    const int sIx   = ord >> 6;         // 0..31 chain position within batch
    const int mB    = bat * NCHAIN + sIx;
    const int mBase = mB * BM;
    const int eBase = eB * BN;

    const int tid  = threadIdx.x;
    const int lane = tid & 63;
    const int w    = tid >> 6;
    const int waveM = (w >> 1) * 64;
    const int waveN = (w & 1) * 64;

    f32x4 acc[4][4] = {};

    // staging: lane tid covers (row = tid>>2, 16B chunk = tid&3)
    const int row0 = tid >> 2, cu = tid & 3;
    const unsigned short* aG0 = xb + (size_t)(mBase + row0) * K_ + cu * 8;
    const unsigned short* aG1 = aG0 + (size_t)64 * K_;
    const unsigned short* bG0 = wb + (size_t)(eBase + row0) * K_ + cu * 8;
    const unsigned short* bG1 = bG0 + (size_t)64 * K_;
    // wave-uniform LDS bases (HW adds lane*16B)
    unsigned short* aL0 = As + (size_t)(w * 64) * 8;
    unsigned short* aL1 = As + (size_t)(256 + w * 64) * 8;
    unsigned short* bL0 = Bs + (size_t)(w * 64) * 8;
    unsigned short* bL1 = Bs + (size_t)(256 + w * 64) * 8;

    const int mrow = lane & 15;
    const int kg   = (lane >> 4) * 8;

    for (int k0 = 0; k0 < K_; k0 += BK) {
        __syncthreads();
        gload16(aG0 + k0, aL0);
        gload16(aG1 + k0, aL1);
        gload16(bG0 + k0, bL0);
        gload16(bG1 + k0, bL1);
        __syncthreads();

        bf16x8 af[4], bfr[4];
#pragma unroll
        for (int i = 0; i < 4; i++)
            af[i] = *(const bf16x8*)(As + (size_t)(waveM + i * 16 + mrow) * BK + kg);
#pragma unroll
        for (int j = 0; j < 4; j++)
            bfr[j] = *(const bf16x8*)(Bs + (size_t)(waveN + j * 16 + mrow) * BK + kg);
#pragma unroll
        for (int i = 0; i < 4; i++)
#pragma unroll
            for (int j = 0; j < 4; j++)
                acc[i][j] = __builtin_amdgcn_mfma_f32_16x16x32_bf16(af[i], bfr[j], acc[i][j], 0, 0, 0);
    }

    // ---- epilogue 1: activation + pack + LDS transpose ----
    const int q    = lane >> 4;
    const int odd  = lane & 1;
    const int colL = (lane & 15) >> 1;            // 0..7
    unsigned int* EpW = &Ep[w][0][0];

#pragma unroll
    for (int i = 0; i < 4; i++) {
#pragma unroll
        for (int j = 0; j < 4; j++) {
            float o0 = __shfl_xor(acc[i][j][0], 1, 64);
            float o1 = __shfl_xor(acc[i][j][1], 1, 64);
            float o2 = __shfl_xor(acc[i][j][2], 1, 64);
            float o3 = __shfl_xor(acc[i][j][3], 1, 64);
            float m0 = odd ? acc[i][j][2] : acc[i][j][0];
            float m1 = odd ? acc[i][j][3] : acc[i][j][1];
            float p0 = odd ? o2 : o0;
            float p1 = odd ? o3 : o1;
            float h0 = odd ? p0 : m0, g0 = odd ? m0 : p0;
            float h1 = odd ? p1 : m1, g1 = odd ? m1 : p1;
            int row = i * 16 + q * 4 + odd * 2;
            int col = j * 8 + colL;
            EpW[(row    ) * 36 + col] = packCV(h0, g0);
            EpW[(row + 1) * 36 + col] = packCV(h1, g1);
        }
    }

    // ---- epilogue 2: quarter reduce (32 rows x 64 ch per thread-group) ----
    __syncthreads();                      // Ep fully written; As/Bs dead -> reuse
    float* scratch = (float*)As;          // [4][64][2] floats = 2 KB
    float* hpre    = scratch + 512;       // 64 floats

    const int dl = tid & 63;              // channel 0..63 within block
    const int qt = tid >> 6;              // quarter 0..3 (rows qt*32 .. +31)
    const int wq = (qt >> 1) * 2 + (dl >> 5);
    const int rB = (qt & 1) * 32;
    const int cc_ = dl & 31;
    const unsigned int* src = &Ep[wq][rB][cc_];
    {
        float C = 1.f, V = 0.f;
#pragma unroll 8
        for (int rr = 0; rr < 32; rr++) {
            union { unsigned int u; f16x2 h; } uu;
            uu.u = src[rr * 36];
            float cv_c = (float)uu.h[0], cv_v = (float)uu.h[1];
            V = fmaf(cv_c, V, cv_v);
            C *= cv_c;
        }
        scratch[(qt * 64 + dl) * 2 + 0] = C;
        scratch[(qt * 64 + dl) * 2 + 1] = V;
    }
    __syncthreads();

    // ---- epilogue 3 (wave 0 only): publish aggregate, then lookback ----
    // Publish is a RELAXED agent-scope 8B atomic: the payload IS the data
    // (sentinel-validated), nothing else is ordered by it -> no fence, no
    // release. (Round-2's __threadfence() triggered per-block L2 inv ->
    // post-fence gload_lds fell from L2-hit to LLC latency; removed.)
    if (tid < 64) {
        float C0 = scratch[(0 * 64 + tid) * 2], V0 = scratch[(0 * 64 + tid) * 2 + 1];
        float C1 = scratch[(1 * 64 + tid) * 2], V1 = scratch[(1 * 64 + tid) * 2 + 1];
        float C2 = scratch[(2 * 64 + tid) * 2], V2 = scratch[(2 * 64 + tid) * 2 + 1];
        float C3 = scratch[(3 * 64 + tid) * 2], V3 = scratch[(3 * 64 + tid) * 2 + 1];
        float Cb = (C0 * C1) * (C2 * C3);
        float Vb = fmaf(C3, fmaf(C2, fmaf(C1, V0, V1), V2), V3);
        union { unsigned long long u; float f[2]; } pk;
        pk.f[0] = Cb; pk.f[1] = Vb;
        // UNCONDITIONAL publish before any wait -> no deadlock possible.
        __hip_atomic_store(&segAgg[(size_t)ord * 64 + tid], pk.u,
                           __ATOMIC_RELAXED, __HIP_MEMORY_SCOPE_AGENT);

        // aggregate-only lookback: fold predecessors t = 0..sIx-1 in order.
        float h = 0.f;
        const size_t chanB = (size_t)inner * 64 + tid;  // (eB*4+bat)*64+ch
#pragma unroll 1
        for (int t0 = 0; t0 < NCHAIN; t0 += 8) {
            if (t0 >= sIx) break;
            unsigned long long vb[8];
#pragma unroll
            for (int k = 0; k < 8; k++)
                vb[k] = (t0 + k < sIx)
                    ? __hip_atomic_load(&segAgg[(size_t)(t0 + k) * 4096 + chanB],
                                        __ATOMIC_RELAXED, __HIP_MEMORY_SCOPE_AGENT)
                    : 0x3f800000ull;    // identity (C=1, V=0)
#pragma unroll
            for (int k = 0; k < 8; k++) {
                if (t0 + k < sIx) {
                    while (vb[k] == SENT)
                        vb[k] = __hip_atomic_load(&segAgg[(size_t)(t0 + k) * 4096 + chanB],
                                                  __ATOMIC_RELAXED, __HIP_MEMORY_SCOPE_AGENT);
                }
            }
#pragma unroll
            for (int k = 0; k < 8; k++) {
                union { unsigned long long u; float f[2]; } qd; qd.u = vb[k];
                h = fmaf(qd.f[0], h, qd.f[1]);
            }
        }
        hpre[tid] = h;
    }
    __syncthreads();

    // ---- epilogue 4: apply h_t = c_t*h_{t-1} + v_t, write out (fp32) ----
    {
        float h = hpre[dl];
        if (qt > 0) h = fmaf(scratch[(0 * 64 + dl) * 2], h, scratch[(0 * 64 + dl) * 2 + 1]);
        if (qt > 1) h = fmaf(scratch[(1 * 64 + dl) * 2], h, scratch[(1 * 64 + dl) * 2 + 1]);
        if (qt > 2) h = fmaf(scratch[(2 * 64 + dl) * 2], h, scratch[(2 * 64 + dl) * 2 + 1]);
        float* outp = out + (size_t)(mBase + qt * 32) * D_ + (eB * 64 + dl);
#pragma unroll 8
        for (int rr = 0; rr < 32; rr++) {
            union { unsigned int u; f16x2 hh; } uu;
            uu.u = src[rr * 36];
            h = fmaf((float)uu.hh[0], h, (float)uu.hh[1]);
            outp[(size_t)rr * D_] = h;
        }
    }
}

// ---------------- launch ----------------
extern "C" void kernel_launch(void* const* d_in, const int* in_sizes, int n_in,
                              void* d_out, int out_size, void* d_ws, size_t ws_size,
                              hipStream_t stream) {
    const float* x = (const float*)d_in[0];
    const float* wmat = (const float*)d_in[1];
    float* out = (float*)d_out;
    char* ws = (char*)d_ws;

    unsigned short* xb = (unsigned short*)(ws);                       // 32 MB @ 0
    unsigned short* wb = (unsigned short*)(ws + (32u << 20));         //  4 MB @ 32M
    unsigned long long* segAgg = (unsigned long long*)(ws + (36u << 20)); // 1 MB @ 36M

    cvt_xw<<<2368, 256, 0, stream>>>(x, xb, wmat, wb, segAgg);
    gemm_fused<<<2048, 256, 0, stream>>>(xb, wb, segAgg, out);
}